// Round 8
// baseline (159.294 us; speedup 1.0000x reference)
//
#include <hip/hip_runtime.h>
#include <math.h>

#define S_ 2
#define V_ 4
#define H_ 1024
#define W_ 1024
#define NCELL 65536
#define NSV 8
#define KSEL 1024
#define CROP_LO 102
#define CROP_HI 922
#define NPIX (H_*W_)

#define NB1 4096             // 12-bit first level
#define NREP 4               // hist1 replicas per sv (atomic-chain cap)
#define HIST_U4 (NSV * NREP * NB1 / 4)   // uint4 words covering hist1

// ws layout (bytes):
//   0      : u32 total
//   64     : u32 sel[8][4]  = {p12, rem1, thr, rem}
//   256    : u32 chunkcnt[8][32]  (1KB)
//   4096   : u8  cnt[512K]   -- reused after k_score as:
//              4096   u32 pix[8][4096] (128KB)
//              135168 u32 rowcnt[2048] (8KB)
//   528384 : u32 keys[512K]              (2 MB)
//   2625536: u32 hist1[8][4][4096]       (512 KB, zeroed by k_count)
//   3674112: u32 list[8][32][2048]       (2 MB, per-chunk segments)
#define OFF_SEL   64
#define OFF_CCNT  256
#define OFF_CNT   4096
#define OFF_PIX   4096
#define OFF_ROW   135168
#define OFF_KEYS  528384
#define OFF_H1    2625536
#define OFF_LIST  3674112

static __device__ __forceinline__ unsigned score_key(float score){
  unsigned ub = __float_as_uint(score);
  return (ub & 0x80000000u) ? ~ub : (ub | 0x80000000u);
}

// Zero the global counter (a kernel, not hipMemsetAsync: fills cost a launch anyway).
__global__ __launch_bounds__(64) void k_init(unsigned* __restrict__ total){
  if (threadIdx.x == 0) *total = 0u;
}

// One thread per coarse cell (4x4 pixels). Counts alpha>0 within crop, writes
// per-cell count, block-reduces into the global total. Spare duty: zero hist1.
__global__ __launch_bounds__(256) void k_count(const float* __restrict__ alpha,
                                               unsigned char* __restrict__ cnt,
                                               unsigned* __restrict__ total,
                                               uint4* __restrict__ histz){
  int g = blockIdx.x * 256 + threadIdx.x;        // 0..524287
  if (g < HIST_U4) histz[g] = make_uint4(0u, 0u, 0u, 0u);
  int sv = g >> 16;
  int cell = g & (NCELL - 1);
  int hc = cell >> 8;
  int wc = cell & 255;
  const float4* ap = reinterpret_cast<const float4*>(alpha);
  int c = 0;
  int x0 = wc * 4;
#pragma unroll
  for (int dy = 0; dy < 4; ++dy){
    int y = hc * 4 + dy;
    float4 a = ap[(size_t)(sv * H_ + y) * (W_ / 4) + wc];
    if (y >= CROP_LO && y < CROP_HI){
      c += (a.x > 0.0f) & (x0 + 0 >= CROP_LO) & (x0 + 0 < CROP_HI);
      c += (a.y > 0.0f) & (x0 + 1 >= CROP_LO) & (x0 + 1 < CROP_HI);
      c += (a.z > 0.0f) & (x0 + 2 >= CROP_LO) & (x0 + 2 < CROP_HI);
      c += (a.w > 0.0f) & (x0 + 3 >= CROP_LO) & (x0 + 3 < CROP_HI);
    }
  }
  cnt[g] = (unsigned char)c;
  __shared__ unsigned red[256];
  red[threadIdx.x] = (unsigned)c;
  __syncthreads();
  for (int off = 128; off > 0; off >>= 1){
    if (threadIdx.x < off) red[threadIdx.x] += red[threadIdx.x + off];
    __syncthreads();
  }
  if (threadIdx.x == 0) atomicAdd(total, red[0]);
}

// Per-cell Gumbel-perturbed score -> order-preserving uint key (pure streaming).
__global__ __launch_bounds__(256) void k_score(const unsigned char* __restrict__ cnt,
                                               const float* __restrict__ gum,
                                               const unsigned* __restrict__ total,
                                               unsigned* __restrict__ keys){
  int g = blockIdx.x * 256 + threadIdx.x;
  float T = (float)(*total);
  float denom = __fadd_rn(T, 1e-8f);
  float inv = __fdiv_rn(1.0f, denom);
  const float COFF = (float)((1.0 - 0.9) / (1024.0 * 1024.0));
  float q_on = __fadd_rn(__fmul_rn(0.9f, inv), COFF);
  int k = cnt[g];
  float pc = __fadd_rn(__fmul_rn((float)k, q_on), __fmul_rn((float)(16 - k), COFF));
  float logp = logf(__fadd_rn(pc, 1e-9f));
  float u = gum[g];
  float gl = logf(__fadd_rn(u, 1e-9f));
  float gmb = -logf(__fadd_rn(-gl, 1e-9f));
  keys[g] = score_key(__fadd_rn(logp, gmb));
}

// 12-bit LDS histogram (u32, 16KB), merged into one of NREP global replicas.
__global__ __launch_bounds__(256) void k_hist1(const unsigned* __restrict__ keys,
                                               unsigned* __restrict__ hist1){
  int sv = blockIdx.x >> 5;        // 32 chunks per sv
  int chunk = blockIdx.x & 31;
  __shared__ unsigned h[NB1];
  for (int i = threadIdx.x; i < NB1; i += 256) h[i] = 0u;
  __syncthreads();
  const uint4* kp = reinterpret_cast<const uint4*>(keys + sv * NCELL + chunk * 2048);
#pragma unroll
  for (int i = 0; i < 2; ++i){
    uint4 k4 = kp[threadIdx.x + i * 256];
    atomicAdd(&h[k4.x >> 20], 1u);
    atomicAdd(&h[k4.y >> 20], 1u);
    atomicAdd(&h[k4.z >> 20], 1u);
    atomicAdd(&h[k4.w >> 20], 1u);
  }
  __syncthreads();
  unsigned* hb = hist1 + (sv * NREP + (chunk & (NREP - 1))) * NB1;
  for (int i = threadIdx.x; i < NB1; i += 256){
    unsigned v = h[i];
    if (v) atomicAdd(&hb[i], v);
  }
}

// Top-12 prefix + remaining count. 8 blocks x 1024 threads; sums NREP replicas.
__global__ __launch_bounds__(1024) void k_pick1(const unsigned* __restrict__ hist1,
                                                unsigned* __restrict__ sel){
  const int sv = blockIdx.x;
  const int t = threadIdx.x;
  const unsigned target = KSEL;
  uint4 b4 = make_uint4(0u, 0u, 0u, 0u);
#pragma unroll
  for (int rep = 0; rep < NREP; ++rep){
    uint4 v = reinterpret_cast<const uint4*>(hist1 + (sv * NREP + rep) * NB1)[t];
    b4.x += v.x; b4.y += v.y; b4.z += v.z; b4.w += v.w;
  }
  unsigned csum = b4.x + b4.y + b4.z + b4.w;
  __shared__ unsigned sh[1024];
  sh[t] = csum;
  __syncthreads();
  for (int off = 1; off < 1024; off <<= 1){
    unsigned v = (t + off < 1024) ? sh[t + off] : 0u;
    __syncthreads();
    sh[t] += v;
    __syncthreads();
  }
  unsigned sufAbove = sh[t] - csum;
  if (sufAbove < target && sh[t] >= target){
    unsigned bb[4] = {b4.x, b4.y, b4.z, b4.w};
    unsigned cum = sufAbove;
    for (int b = 3; b >= 0; --b){
      unsigned hv = bb[b];
      cum += hv;
      if (cum >= target){
        sel[sv * 4 + 0] = (unsigned)(t * 4 + b);    // p12
        sel[sv * 4 + 1] = target - (cum - hv);      // rem1
        break;
      }
    }
  }
}

// Compact keys matching p12 into per-chunk segments (LDS counter, no global atomics).
__global__ __launch_bounds__(256) void k_compact(const unsigned* __restrict__ keys,
                                                 const unsigned* __restrict__ sel,
                                                 unsigned* __restrict__ list,
                                                 unsigned* __restrict__ chunkcnt){
  int sv = blockIdx.x >> 5;
  int chunk = blockIdx.x & 31;
  unsigned p12 = sel[sv * 4 + 0];
  __shared__ unsigned lcnt;
  if (threadIdx.x == 0) lcnt = 0u;
  __syncthreads();
  const uint4* kp = reinterpret_cast<const uint4*>(keys + sv * NCELL + chunk * 2048);
  unsigned* seg = list + (sv * 32 + chunk) * 2048;
#pragma unroll
  for (int i = 0; i < 2; ++i){
    uint4 k4 = kp[threadIdx.x + i * 256];
    unsigned kk[4] = {k4.x, k4.y, k4.z, k4.w};
#pragma unroll
    for (int q = 0; q < 4; ++q){
      if ((kk[q] >> 20) == p12) seg[atomicAdd(&lcnt, 1u)] = kk[q];
    }
  }
  __syncthreads();
  if (threadIdx.x == 0) chunkcnt[sv * 32 + chunk] = lcnt;
}

// Exact 32-bit threshold + tie count among compacted candidates (n ~ hundreds).
// Value-based (order-independent): thr = v with #(>v) < rem1 <= #(>v)+#(==v).
__global__ __launch_bounds__(1024) void k_pick2b(const unsigned* __restrict__ list,
                                                 const unsigned* __restrict__ chunkcnt,
                                                 unsigned* __restrict__ sel){
  const int sv = blockIdx.x;
  const int t = threadIdx.x;
  __shared__ unsigned pfx[33];
  __shared__ unsigned seg[2048];
  if (t == 0){
    unsigned a = 0;
    for (int c = 0; c < 32; ++c){ pfx[c] = a; a += chunkcnt[sv * 32 + c]; }
    pfx[32] = a;
  }
  __syncthreads();
  const unsigned n = pfx[32];
  const unsigned rem1 = sel[sv * 4 + 1];
  const unsigned nbatch = (n + 1023u) / 1024u;
  for (unsigned b = 0; b < nbatch; ++b){
    unsigned i = b * 1024u + (unsigned)t;
    unsigned vi = 0u;
    bool valid = (i < n);
    if (valid){
      int c = 0;
      while (c < 31 && pfx[c + 1] <= i) ++c;
      vi = list[(sv * 32 + c) * 2048 + (i - pfx[c])];
    }
    unsigned cgt = 0, ceq = 0;
    for (int jc = 0; jc < 32; ++jc){
      unsigned mj = pfx[jc + 1] - pfx[jc];
      const unsigned* gseg = list + (sv * 32 + jc) * 2048;
      for (unsigned j = t; j < mj; j += 1024) seg[j] = gseg[j];
      __syncthreads();
      if (valid){
        for (unsigned j = 0; j < mj; ++j){
          unsigned w = seg[j];
          cgt += (w > vi);
          ceq += (w == vi);
        }
      }
      __syncthreads();
    }
    if (valid && cgt < rem1 && rem1 <= cgt + ceq){
      sel[sv * 4 + 2] = vi;            // thr (duplicates write identical values)
      sel[sv * 4 + 3] = rem1 - cgt;    // rem
    }
  }
}

// One wave per coarse row: count gt/eq vs thr, packed (gt<<16)|eq.
__global__ __launch_bounds__(256) void k_rowcnt(const unsigned* __restrict__ keys,
                                                const unsigned* __restrict__ sel,
                                                unsigned* __restrict__ rowcnt){
  int gw = blockIdx.x * 4 + (threadIdx.x >> 6);   // global row id 0..2047
  int lane = threadIdx.x & 63;
  int sv = gw >> 8;
  int row = gw & 255;
  const unsigned thr = sel[sv * 4 + 2];
  uint4 k4 = *reinterpret_cast<const uint4*>(keys + sv * NCELL + row * 256 + lane * 4);
  unsigned gt = (k4.x > thr) + (k4.y > thr) + (k4.z > thr) + (k4.w > thr);
  unsigned eq = (k4.x == thr) + (k4.y == thr) + (k4.z == thr) + (k4.w == thr);
  unsigned p = (gt << 16) | eq;
#pragma unroll
  for (int off = 1; off < 64; off <<= 1) p += __shfl_xor(p, off, 64);
  if (lane == 0) rowcnt[gw] = p;
}

// 4-wave exclusive scan over a 256-value block (thread t holds v for row t).
static __device__ __forceinline__ unsigned block_excl_scan256(unsigned v, unsigned* lds4, int t){
  int lane = t & 63, w = t >> 6;
  unsigned x = v;
#pragma unroll
  for (int off = 1; off < 64; off <<= 1){
    unsigned y = __shfl_up(x, (unsigned)off, 64);
    if (lane >= off) x += y;
  }
  if (lane == 63) lds4[w] = x;
  __syncthreads();
  unsigned base = 0;
  for (int i = 0; i < w; ++i) base += lds4[i];
  __syncthreads();
  return base + x - v;
}

// 512 blocks (64 per sv, 4 waves each = one wave per row). Scans from rowcnt,
// then each wave emits its row's selected cells (flat pixel index per rank).
__global__ __launch_bounds__(256) void k_emit2(const unsigned* __restrict__ keys,
                                               const unsigned* __restrict__ sel,
                                               const unsigned* __restrict__ rowcnt,
                                               const int* __restrict__ fidx,
                                               unsigned* __restrict__ pix){
  const int sv = blockIdx.x >> 6;
  const int t = threadIdx.x;
  __shared__ unsigned lds4[4];
  __shared__ unsigned sM[256], sP[256], sEqb[256];

  const unsigned thr = sel[sv * 4 + 2];
  const unsigned rem = sel[sv * 4 + 3];

  unsigned rc = rowcnt[sv * 256 + t];
  unsigned gt = rc >> 16, eq = rc & 0xFFFFu;
  unsigned eqbase = block_excl_scan256(eq, lds4, t);
  unsigned take_eq = 0;
  if (rem > eqbase){ take_eq = rem - eqbase; if (take_eq > eq) take_eq = eq; }
  unsigned m = gt + take_eq;
  unsigned P = block_excl_scan256(m, lds4, t);
  sM[t] = m; sP[t] = P; sEqb[t] = eqbase;
  __syncthreads();

  const int lane = t & 63;
  const int row = ((blockIdx.x & 63) << 2) + (t >> 6);
  const unsigned rm = sM[row];
  const unsigned rP = sP[row];
  const unsigned reqb = sEqb[row];

  const int fi = fidx[sv];
  const int k1 = (fi >> 1) & 1;
  const int k2 = fi & 1;
  unsigned* pb = pix + sv * 4096;

  uint4 k4 = *reinterpret_cast<const uint4*>(keys + sv * NCELL + row * 256 + lane * 4);
  unsigned kk[4] = {k4.x, k4.y, k4.z, k4.w};

  unsigned laneEq = 0;
#pragma unroll
  for (int q = 0; q < 4; ++q) laneEq += (kk[q] == thr);
  unsigned xe = laneEq;
#pragma unroll
  for (int off = 1; off < 64; off <<= 1){
    unsigned y = __shfl_up(xe, (unsigned)off, 64);
    if (lane >= off) xe += y;
  }
  unsigned eqpre = xe - laneEq;

  bool s[4];
  unsigned eqr = reqb + eqpre;
  unsigned laneSel = 0;
#pragma unroll
  for (int q = 0; q < 4; ++q){
    bool sq = (kk[q] > thr);
    if (kk[q] == thr){ if (eqr < rem) sq = true; eqr++; }
    s[q] = sq;
    laneSel += sq;
  }
  unsigned xs = laneSel;
#pragma unroll
  for (int off = 1; off < 64; off <<= 1){
    unsigned y = __shfl_up(xs, (unsigned)off, 64);
    if (lane >= off) xs += y;
  }
  unsigned jj = xs - laneSel;

  const unsigned baserank = 4u * rP;
#pragma unroll
  for (int q = 0; q < 4; ++q){
    if (!s[q]) continue;
    int wc = lane * 4 + q;
    unsigned base = baserank + 2u * jj;
    unsigned f0 = (unsigned)((4 * row + k1) * W_ + 4 * wc + k2);
    pb[base + 0]           = f0;
    pb[base + 1]           = f0 + 2u;
    pb[base + 2u * rm + 0] = f0 + 2u * W_;
    pb[base + 2u * rm + 1] = f0 + 2u * W_ + 2u;
    jj++;
  }
}

// One thread per output rank: gather uv, ray math, write all outputs.
__global__ __launch_bounds__(256) void k_rays(const unsigned* __restrict__ pix,
                                              const float* __restrict__ uv,
                                              const float* __restrict__ intr,
                                              const float* __restrict__ extr,
                                              float* __restrict__ out){
  int g = blockIdx.x * 256 + threadIdx.x;   // 0..32767
  int sv = g >> 12;
  int r = g & 4095;
  const int s = sv >> 2;
  const float fx = intr[s * 16 + 0];
  const float cx = intr[s * 16 + 2];
  const float fy = intr[s * 16 + 5];
  const float cy = intr[s * 16 + 6];
  const float e00 = extr[sv * 16 + 0], e01 = extr[sv * 16 + 1], e02 = extr[sv * 16 + 2], e03 = extr[sv * 16 + 3];
  const float e10 = extr[sv * 16 + 4], e11 = extr[sv * 16 + 5], e12 = extr[sv * 16 + 6], e13 = extr[sv * 16 + 7];
  const float e20 = extr[sv * 16 + 8], e21 = extr[sv * 16 + 9], e22 = extr[sv * 16 + 10], e23 = extr[sv * 16 + 11];
  if (r < 3) out[sv * 3 + r] = extr[sv * 16 + r * 4 + 3];  // ray_start

  unsigned flat = pix[g];
  const float* uvx = uv + (size_t)sv * 2 * NPIX;
  const float* uvy = uvx + NPIX;
  float X = uvx[flat];
  float Y = uvy[flat];
  float* out_dir = out + S_ * V_ * 3;
  float* out_uvs = out + S_ * V_ * 3 + S_ * V_ * 4096 * 3;
  out_uvs[(sv * 2 + 0) * 4096 + r] = X;
  out_uvs[(sv * 2 + 1) * 4096 + r] = Y;
  float xx = (X - cx) / fx;
  float yy = (Y - cy) / fy;
  float d0 = (e00 * xx + e01 * yy + e02 + e03) - e03;
  float d1 = (e10 * xx + e11 * yy + e12 + e13) - e13;
  float d2 = (e20 * xx + e21 * yy + e22 + e23) - e23;
  float nrm = sqrtf(d0 * d0 + d1 * d1 + d2 * d2);
  float den = fmaxf(nrm, 1e-12f);
  size_t ob = ((size_t)sv * 4096 + r) * 3;
  out_dir[ob + 0] = d0 / den;
  out_dir[ob + 1] = d1 / den;
  out_dir[ob + 2] = d2 / den;
}

extern "C" void kernel_launch(void* const* d_in, const int* in_sizes, int n_in,
                              void* d_out, int out_size, void* d_ws, size_t ws_size,
                              hipStream_t stream){
  (void)in_sizes; (void)n_in; (void)out_size; (void)ws_size;
  const float* uv         = (const float*)d_in[0];
  const float* intr       = (const float*)d_in[1];
  const float* extr       = (const float*)d_in[2];
  const float* alpha      = (const float*)d_in[3];
  const float* gum        = (const float*)d_in[5];
  const int*   full_index = (const int*)d_in[6];
  float* out = (float*)d_out;

  char* ws = (char*)d_ws;
  unsigned*      total    = (unsigned*)ws;
  unsigned*      sel      = (unsigned*)(ws + OFF_SEL);
  unsigned*      chunkcnt = (unsigned*)(ws + OFF_CCNT);
  unsigned char* cnt      = (unsigned char*)(ws + OFF_CNT);
  unsigned*      pix      = (unsigned*)(ws + OFF_PIX);
  unsigned*      rowcnt   = (unsigned*)(ws + OFF_ROW);
  unsigned*      keys     = (unsigned*)(ws + OFF_KEYS);
  unsigned*      hist1    = (unsigned*)(ws + OFF_H1);
  uint4*         histz4   = (uint4*)(ws + OFF_H1);
  unsigned*      list     = (unsigned*)(ws + OFF_LIST);

  hipLaunchKernelGGL(k_init,    dim3(1), dim3(64), 0, stream, total);
  hipLaunchKernelGGL(k_count,   dim3(NSV * NCELL / 256), dim3(256), 0, stream, alpha, cnt, total, histz4);
  hipLaunchKernelGGL(k_score,   dim3(NSV * NCELL / 256), dim3(256), 0, stream, cnt, gum, total, keys);
  hipLaunchKernelGGL(k_hist1,   dim3(NSV * 32), dim3(256), 0, stream, keys, hist1);
  hipLaunchKernelGGL(k_pick1,   dim3(NSV), dim3(1024), 0, stream, hist1, sel);
  hipLaunchKernelGGL(k_compact, dim3(NSV * 32), dim3(256), 0, stream, keys, sel, list, chunkcnt);
  hipLaunchKernelGGL(k_pick2b,  dim3(NSV), dim3(1024), 0, stream, list, chunkcnt, sel);
  hipLaunchKernelGGL(k_rowcnt,  dim3(512), dim3(256), 0, stream, keys, sel, rowcnt);
  hipLaunchKernelGGL(k_emit2,   dim3(512), dim3(256), 0, stream, keys, sel, rowcnt, full_index, pix);
  hipLaunchKernelGGL(k_rays,    dim3(NSV * 4096 / 256), dim3(256), 0, stream, pix, uv, intr, extr, out);
}

// Round 9
// 76.927 us; speedup vs baseline: 2.0707x; 2.0707x over previous
//
#include <hip/hip_runtime.h>
#include <math.h>

#define S_ 2
#define V_ 4
#define H_ 1024
#define W_ 1024
#define NCELL 65536
#define NSV 8
#define KSEL 1024
#define CROP_LO 102
#define CROP_HI 922
#define NPIX (H_*W_)

#define NB1 32768            // 15-bit first level
#define NB2 131072           // 17-bit second level
#define NSEG 128             // hist2 segments per sv (1024 buckets each)
#define HIST_U4 ((NB1 + NB2) * NSV / 4)   // uint4 words covering hist1+hist2 (contiguous)

// ws layout (bytes):
//   0      : u32 total
//   64     : u32 sel[8][4]  = {p15, rem1, thr, rem}
//   256    : u32 segsum[8][128] (4KB)
//   4352   : u8  cnt[512K]   -- reused after k_score as:
//              4352   u32 pix[8][4096] (128KB)
//              135424 u32 rowcnt[2048] (8KB)
//   528640 : u32 keys[512K]          (2 MB)
//   2625792: u32 hist1[8][32768]     (1 MB)
//   3674368: u32 hist2[8][131072]    (4 MB)   -- contiguous after hist1
#define OFF_SEL   64
#define OFF_SEG   256
#define OFF_CNT   4352
#define OFF_PIX   4352
#define OFF_ROW   135424
#define OFF_KEYS  528640
#define OFF_H1    2625792
#define OFF_H2    3674368

static __device__ __forceinline__ unsigned score_key(float score){
  unsigned ub = __float_as_uint(score);
  return (ub & 0x80000000u) ? ~ub : (ub | 0x80000000u);
}

// Zero the global counter (kernel, not hipMemsetAsync).
__global__ __launch_bounds__(64) void k_init(unsigned* __restrict__ total){
  if (threadIdx.x == 0) *total = 0u;
}

// One thread per coarse cell (4x4 pixels). Counts alpha>0 within crop, writes
// per-cell count, block-reduces into the global total (exact: integer sum < 2^24).
__global__ __launch_bounds__(256) void k_count(const float* __restrict__ alpha,
                                               unsigned char* __restrict__ cnt,
                                               unsigned* __restrict__ total){
  int g = blockIdx.x * 256 + threadIdx.x;        // 0..524287
  int sv = g >> 16;
  int cell = g & (NCELL - 1);
  int hc = cell >> 8;
  int wc = cell & 255;
  const float4* ap = reinterpret_cast<const float4*>(alpha);
  int c = 0;
  int x0 = wc * 4;
#pragma unroll
  for (int dy = 0; dy < 4; ++dy){
    int y = hc * 4 + dy;
    float4 a = ap[(size_t)(sv * H_ + y) * (W_ / 4) + wc];
    if (y >= CROP_LO && y < CROP_HI){
      c += (a.x > 0.0f) & (x0 + 0 >= CROP_LO) & (x0 + 0 < CROP_HI);
      c += (a.y > 0.0f) & (x0 + 1 >= CROP_LO) & (x0 + 1 < CROP_HI);
      c += (a.z > 0.0f) & (x0 + 2 >= CROP_LO) & (x0 + 2 < CROP_HI);
      c += (a.w > 0.0f) & (x0 + 3 >= CROP_LO) & (x0 + 3 < CROP_HI);
    }
  }
  cnt[g] = (unsigned char)c;
  __shared__ unsigned red[256];
  red[threadIdx.x] = (unsigned)c;
  __syncthreads();
  for (int off = 128; off > 0; off >>= 1){
    if (threadIdx.x < off) red[threadIdx.x] += red[threadIdx.x + off];
    __syncthreads();
  }
  if (threadIdx.x == 0) atomicAdd(total, red[0]);
}

// Per-cell Gumbel-perturbed score -> order-preserving uint key (pure streaming).
// Also zeroes the hist1+hist2 region (one uint4 store per thread).
__global__ __launch_bounds__(256) void k_score(const unsigned char* __restrict__ cnt,
                                               const float* __restrict__ gum,
                                               const unsigned* __restrict__ total,
                                               unsigned* __restrict__ keys,
                                               uint4* __restrict__ histz){
  int g = blockIdx.x * 256 + threadIdx.x;
  if (g < HIST_U4) histz[g] = make_uint4(0u, 0u, 0u, 0u);
  float T = (float)(*total);
  float denom = __fadd_rn(T, 1e-8f);
  float inv = __fdiv_rn(1.0f, denom);
  const float COFF = (float)((1.0 - 0.9) / (1024.0 * 1024.0));
  float q_on = __fadd_rn(__fmul_rn(0.9f, inv), COFF);
  int k = cnt[g];
  float pc = __fadd_rn(__fmul_rn((float)k, q_on), __fmul_rn((float)(16 - k), COFF));
  float logp = logf(__fadd_rn(pc, 1e-9f));
  float u = gum[g];
  float gl = logf(__fadd_rn(u, 1e-9f));
  float gmb = -logf(__fadd_rn(-gl, 1e-9f));
  keys[g] = score_key(__fadd_rn(logp, gmb));
}

// LDS-privatized 15-bit histogram (packed u16), merged to global u32 hist1.
__global__ __launch_bounds__(256) void k_hist1(const unsigned* __restrict__ keys,
                                               unsigned* __restrict__ hist1){
  int sv = blockIdx.x >> 5;        // 32 chunks per sv
  int chunk = blockIdx.x & 31;
  __shared__ unsigned h[NB1 / 2];  // 32768 u16 counts, 64KB
  for (int i = threadIdx.x; i < NB1 / 2; i += 256) h[i] = 0u;
  __syncthreads();
  const uint4* kp = reinterpret_cast<const uint4*>(keys + sv * NCELL + chunk * 2048);
#pragma unroll
  for (int i = 0; i < 2; ++i){
    uint4 k4 = kp[threadIdx.x + i * 256];
    unsigned b;
    b = k4.x >> 17; atomicAdd(&h[b >> 1], 1u << ((b & 1u) << 4));
    b = k4.y >> 17; atomicAdd(&h[b >> 1], 1u << ((b & 1u) << 4));
    b = k4.z >> 17; atomicAdd(&h[b >> 1], 1u << ((b & 1u) << 4));
    b = k4.w >> 17; atomicAdd(&h[b >> 1], 1u << ((b & 1u) << 4));
  }
  __syncthreads();
  unsigned* hb = hist1 + sv * NB1;
  for (int i = threadIdx.x; i < NB1 / 2; i += 256){
    unsigned w = h[i];
    unsigned lo = w & 0xFFFFu, hi = w >> 16;
    if (lo) atomicAdd(&hb[2 * i + 0], lo);
    if (hi) atomicAdd(&hb[2 * i + 1], hi);
  }
}

// Find top-15 prefix + remaining count from the 32768-bucket histogram. 1024 threads.
__global__ __launch_bounds__(1024) void k_pick1(const unsigned* __restrict__ hist1,
                                                unsigned* __restrict__ sel){
  const int sv = blockIdx.x;
  const int t = threadIdx.x;
  const unsigned* h = hist1 + sv * NB1;
  const unsigned target = KSEL;
  const uint4* h4 = reinterpret_cast<const uint4*>(h + t * 32);
  unsigned csum = 0;
#pragma unroll
  for (int i = 0; i < 8; ++i){
    uint4 v = h4[i];
    csum += v.x + v.y + v.z + v.w;
  }
  __shared__ unsigned sh[1024];
  sh[t] = csum;
  __syncthreads();
  for (int off = 1; off < 1024; off <<= 1){
    unsigned v = (t + off < 1024) ? sh[t + off] : 0u;
    __syncthreads();
    sh[t] += v;
    __syncthreads();
  }
  unsigned sufAbove = sh[t] - csum;
  if (sufAbove < target && sh[t] >= target){
    unsigned cum = sufAbove;
    for (int b = 31; b >= 0; --b){
      unsigned hv = h[t * 32 + b];
      cum += hv;
      if (cum >= target){
        sel[sv * 4 + 0] = (unsigned)(t * 32 + b);   // p15
        sel[sv * 4 + 1] = target - (cum - hv);      // rem1
        break;
      }
    }
  }
}

// Histogram of low 17 bits among keys whose top 15 bits == p15 (sparse -> no contention).
__global__ __launch_bounds__(256) void k_hist2(const unsigned* __restrict__ keys,
                                               const unsigned* __restrict__ sel,
                                               unsigned* __restrict__ hist2){
  int sv = blockIdx.x >> 5;
  int chunk = blockIdx.x & 31;
  unsigned p15 = sel[sv * 4 + 0];
  const uint4* kp = reinterpret_cast<const uint4*>(keys + sv * NCELL + chunk * 2048);
  unsigned* hb = hist2 + sv * NB2;
#pragma unroll
  for (int i = 0; i < 2; ++i){
    uint4 k4 = kp[threadIdx.x + i * 256];
    if ((k4.x >> 17) == p15) atomicAdd(&hb[k4.x & 0x1FFFFu], 1u);
    if ((k4.y >> 17) == p15) atomicAdd(&hb[k4.y & 0x1FFFFu], 1u);
    if ((k4.z >> 17) == p15) atomicAdd(&hb[k4.z & 0x1FFFFu], 1u);
    if ((k4.w >> 17) == p15) atomicAdd(&hb[k4.w & 0x1FFFFu], 1u);
  }
}

// Wide partial sums of hist2: 1024 blocks, each sums one 1024-bucket segment.
__global__ __launch_bounds__(256) void k_seg2(const unsigned* __restrict__ hist2,
                                              unsigned* __restrict__ segsum){
  int sv = blockIdx.x >> 7;        // 128 segments per sv
  int seg = blockIdx.x & (NSEG - 1);
  const uint4* h4 = reinterpret_cast<const uint4*>(hist2 + sv * NB2 + seg * 1024);
  uint4 v = h4[threadIdx.x];
  unsigned csum = v.x + v.y + v.z + v.w;
  __shared__ unsigned red[256];
  red[threadIdx.x] = csum;
  __syncthreads();
  for (int off = 128; off > 0; off >>= 1){
    if (threadIdx.x < off) red[threadIdx.x] += red[threadIdx.x + off];
    __syncthreads();
  }
  if (threadIdx.x == 0) segsum[sv * NSEG + seg] = red[0];
}

// Exact 32-bit threshold + tie count: suffix over 128 segment sums (serial),
// then a 256-thread scan of only the winning 1024-bucket segment (4KB).
// Algebraically identical to the monolithic suffix scan over all 131072 buckets.
__global__ __launch_bounds__(256) void k_pick2c(const unsigned* __restrict__ hist2,
                                                const unsigned* __restrict__ segsum,
                                                unsigned* __restrict__ sel){
  const int sv = blockIdx.x;
  const int t = threadIdx.x;
  __shared__ unsigned ss[NSEG];
  __shared__ int swin;
  __shared__ unsigned stgt;
  if (t < NSEG) ss[t] = segsum[sv * NSEG + t];
  __syncthreads();
  if (t == 0){
    unsigned target = sel[sv * 4 + 1];
    unsigned cum = 0;
    for (int s = NSEG - 1; s >= 0; --s){
      cum += ss[s];
      if (cum >= target){ swin = s; stgt = target - (cum - ss[s]); break; }
    }
  }
  __syncthreads();
  const int s = swin;
  const unsigned t2 = stgt;
  const uint4* h4 = reinterpret_cast<const uint4*>(hist2 + sv * NB2 + s * 1024);
  uint4 v = h4[t];
  unsigned csum = v.x + v.y + v.z + v.w;
  __shared__ unsigned sh[256];
  sh[t] = csum;
  __syncthreads();
  for (int off = 1; off < 256; off <<= 1){
    unsigned y = (t + off < 256) ? sh[t + off] : 0u;
    __syncthreads();
    sh[t] += y;
    __syncthreads();
  }
  unsigned sufAbove = sh[t] - csum;
  if (sufAbove < t2 && sh[t] >= t2){
    unsigned bb[4] = {v.x, v.y, v.z, v.w};
    unsigned cum = sufAbove;
    for (int b = 3; b >= 0; --b){
      cum += bb[b];
      if (cum >= t2){
        sel[sv * 4 + 2] = (sel[sv * 4 + 0] << 17) | (unsigned)(s * 1024 + t * 4 + b); // thr
        sel[sv * 4 + 3] = t2 - (cum - bb[b]);                                          // rem
        break;
      }
    }
  }
}

// One wave per coarse row: count gt/eq vs thr, packed (gt<<16)|eq.
__global__ __launch_bounds__(256) void k_rowcnt(const unsigned* __restrict__ keys,
                                                const unsigned* __restrict__ sel,
                                                unsigned* __restrict__ rowcnt){
  int gw = blockIdx.x * 4 + (threadIdx.x >> 6);   // global row id 0..2047
  int lane = threadIdx.x & 63;
  int sv = gw >> 8;
  int row = gw & 255;
  const unsigned thr = sel[sv * 4 + 2];
  uint4 k4 = *reinterpret_cast<const uint4*>(keys + sv * NCELL + row * 256 + lane * 4);
  unsigned gt = (k4.x > thr) + (k4.y > thr) + (k4.z > thr) + (k4.w > thr);
  unsigned eq = (k4.x == thr) + (k4.y == thr) + (k4.z == thr) + (k4.w == thr);
  unsigned p = (gt << 16) | eq;
#pragma unroll
  for (int off = 1; off < 64; off <<= 1) p += __shfl_xor(p, off, 64);
  if (lane == 0) rowcnt[gw] = p;
}

// 4-wave exclusive scan over a 256-value block (thread t holds v for row t).
static __device__ __forceinline__ unsigned block_excl_scan256(unsigned v, unsigned* lds4, int t){
  int lane = t & 63, w = t >> 6;
  unsigned x = v;
#pragma unroll
  for (int off = 1; off < 64; off <<= 1){
    unsigned y = __shfl_up(x, (unsigned)off, 64);
    if (lane >= off) x += y;
  }
  if (lane == 63) lds4[w] = x;
  __syncthreads();
  unsigned base = 0;
  for (int i = 0; i < w; ++i) base += lds4[i];
  __syncthreads();
  return base + x - v;
}

// 512 blocks (64 per sv, 4 waves each = one wave per row). Scans from rowcnt,
// then each wave emits its row's selected cells (flat pixel index per rank).
__global__ __launch_bounds__(256) void k_emit2(const unsigned* __restrict__ keys,
                                               const unsigned* __restrict__ sel,
                                               const unsigned* __restrict__ rowcnt,
                                               const int* __restrict__ fidx,
                                               unsigned* __restrict__ pix){
  const int sv = blockIdx.x >> 6;
  const int t = threadIdx.x;
  __shared__ unsigned lds4[4];
  __shared__ unsigned sM[256], sP[256], sEqb[256];

  const unsigned thr = sel[sv * 4 + 2];
  const unsigned rem = sel[sv * 4 + 3];

  unsigned rc = rowcnt[sv * 256 + t];
  unsigned gt = rc >> 16, eq = rc & 0xFFFFu;
  unsigned eqbase = block_excl_scan256(eq, lds4, t);
  unsigned take_eq = 0;
  if (rem > eqbase){ take_eq = rem - eqbase; if (take_eq > eq) take_eq = eq; }
  unsigned m = gt + take_eq;
  unsigned P = block_excl_scan256(m, lds4, t);
  sM[t] = m; sP[t] = P; sEqb[t] = eqbase;
  __syncthreads();

  const int lane = t & 63;
  const int row = ((blockIdx.x & 63) << 2) + (t >> 6);
  const unsigned rm = sM[row];
  const unsigned rP = sP[row];
  const unsigned reqb = sEqb[row];

  const int fi = fidx[sv];
  const int k1 = (fi >> 1) & 1;
  const int k2 = fi & 1;
  unsigned* pb = pix + sv * 4096;

  uint4 k4 = *reinterpret_cast<const uint4*>(keys + sv * NCELL + row * 256 + lane * 4);
  unsigned kk[4] = {k4.x, k4.y, k4.z, k4.w};

  unsigned laneEq = 0;
#pragma unroll
  for (int q = 0; q < 4; ++q) laneEq += (kk[q] == thr);
  unsigned xe = laneEq;
#pragma unroll
  for (int off = 1; off < 64; off <<= 1){
    unsigned y = __shfl_up(xe, (unsigned)off, 64);
    if (lane >= off) xe += y;
  }
  unsigned eqpre = xe - laneEq;

  bool s[4];
  unsigned eqr = reqb + eqpre;
  unsigned laneSel = 0;
#pragma unroll
  for (int q = 0; q < 4; ++q){
    bool sq = (kk[q] > thr);
    if (kk[q] == thr){ if (eqr < rem) sq = true; eqr++; }
    s[q] = sq;
    laneSel += sq;
  }
  unsigned xs = laneSel;
#pragma unroll
  for (int off = 1; off < 64; off <<= 1){
    unsigned y = __shfl_up(xs, (unsigned)off, 64);
    if (lane >= off) xs += y;
  }
  unsigned jj = xs - laneSel;

  const unsigned baserank = 4u * rP;
#pragma unroll
  for (int q = 0; q < 4; ++q){
    if (!s[q]) continue;
    int wc = lane * 4 + q;
    unsigned base = baserank + 2u * jj;
    unsigned f0 = (unsigned)((4 * row + k1) * W_ + 4 * wc + k2);
    pb[base + 0]           = f0;
    pb[base + 1]           = f0 + 2u;
    pb[base + 2u * rm + 0] = f0 + 2u * W_;
    pb[base + 2u * rm + 1] = f0 + 2u * W_ + 2u;
    jj++;
  }
}

// One thread per output rank: gather uv, ray math, write all outputs.
__global__ __launch_bounds__(256) void k_rays(const unsigned* __restrict__ pix,
                                              const float* __restrict__ uv,
                                              const float* __restrict__ intr,
                                              const float* __restrict__ extr,
                                              float* __restrict__ out){
  int g = blockIdx.x * 256 + threadIdx.x;   // 0..32767
  int sv = g >> 12;
  int r = g & 4095;
  const int s = sv >> 2;
  const float fx = intr[s * 16 + 0];
  const float cx = intr[s * 16 + 2];
  const float fy = intr[s * 16 + 5];
  const float cy = intr[s * 16 + 6];
  const float e00 = extr[sv * 16 + 0], e01 = extr[sv * 16 + 1], e02 = extr[sv * 16 + 2], e03 = extr[sv * 16 + 3];
  const float e10 = extr[sv * 16 + 4], e11 = extr[sv * 16 + 5], e12 = extr[sv * 16 + 6], e13 = extr[sv * 16 + 7];
  const float e20 = extr[sv * 16 + 8], e21 = extr[sv * 16 + 9], e22 = extr[sv * 16 + 10], e23 = extr[sv * 16 + 11];
  if (r < 3) out[sv * 3 + r] = extr[sv * 16 + r * 4 + 3];  // ray_start

  unsigned flat = pix[g];
  const float* uvx = uv + (size_t)sv * 2 * NPIX;
  const float* uvy = uvx + NPIX;
  float X = uvx[flat];
  float Y = uvy[flat];
  float* out_dir = out + S_ * V_ * 3;
  float* out_uvs = out + S_ * V_ * 3 + S_ * V_ * 4096 * 3;
  out_uvs[(sv * 2 + 0) * 4096 + r] = X;
  out_uvs[(sv * 2 + 1) * 4096 + r] = Y;
  float xx = (X - cx) / fx;
  float yy = (Y - cy) / fy;
  float d0 = (e00 * xx + e01 * yy + e02 + e03) - e03;
  float d1 = (e10 * xx + e11 * yy + e12 + e13) - e13;
  float d2 = (e20 * xx + e21 * yy + e22 + e23) - e23;
  float nrm = sqrtf(d0 * d0 + d1 * d1 + d2 * d2);
  float den = fmaxf(nrm, 1e-12f);
  size_t ob = ((size_t)sv * 4096 + r) * 3;
  out_dir[ob + 0] = d0 / den;
  out_dir[ob + 1] = d1 / den;
  out_dir[ob + 2] = d2 / den;
}

extern "C" void kernel_launch(void* const* d_in, const int* in_sizes, int n_in,
                              void* d_out, int out_size, void* d_ws, size_t ws_size,
                              hipStream_t stream){
  (void)in_sizes; (void)n_in; (void)out_size; (void)ws_size;
  const float* uv         = (const float*)d_in[0];
  const float* intr       = (const float*)d_in[1];
  const float* extr       = (const float*)d_in[2];
  const float* alpha      = (const float*)d_in[3];
  const float* gum        = (const float*)d_in[5];
  const int*   full_index = (const int*)d_in[6];
  float* out = (float*)d_out;

  char* ws = (char*)d_ws;
  unsigned*      total  = (unsigned*)ws;
  unsigned*      sel    = (unsigned*)(ws + OFF_SEL);
  unsigned*      segsum = (unsigned*)(ws + OFF_SEG);
  unsigned char* cnt    = (unsigned char*)(ws + OFF_CNT);
  unsigned*      pix    = (unsigned*)(ws + OFF_PIX);
  unsigned*      rowcnt = (unsigned*)(ws + OFF_ROW);
  unsigned*      keys   = (unsigned*)(ws + OFF_KEYS);
  unsigned*      hist1  = (unsigned*)(ws + OFF_H1);
  unsigned*      hist2  = (unsigned*)(ws + OFF_H2);
  uint4*         histz  = (uint4*)(ws + OFF_H1);       // hist1+hist2, zeroed in k_score

  hipLaunchKernelGGL(k_init,   dim3(1), dim3(64), 0, stream, total);
  hipLaunchKernelGGL(k_count,  dim3(NSV * NCELL / 256), dim3(256), 0, stream, alpha, cnt, total);
  hipLaunchKernelGGL(k_score,  dim3(NSV * NCELL / 256), dim3(256), 0, stream, cnt, gum, total, keys, histz);
  hipLaunchKernelGGL(k_hist1,  dim3(NSV * 32), dim3(256), 0, stream, keys, hist1);
  hipLaunchKernelGGL(k_pick1,  dim3(NSV), dim3(1024), 0, stream, hist1, sel);
  hipLaunchKernelGGL(k_hist2,  dim3(NSV * 32), dim3(256), 0, stream, keys, sel, hist2);
  hipLaunchKernelGGL(k_seg2,   dim3(NSV * NSEG), dim3(256), 0, stream, hist2, segsum);
  hipLaunchKernelGGL(k_pick2c, dim3(NSV), dim3(256), 0, stream, hist2, segsum, sel);
  hipLaunchKernelGGL(k_rowcnt, dim3(512), dim3(256), 0, stream, keys, sel, rowcnt);
  hipLaunchKernelGGL(k_emit2,  dim3(512), dim3(256), 0, stream, keys, sel, rowcnt, full_index, pix);
  hipLaunchKernelGGL(k_rays,   dim3(NSV * 4096 / 256), dim3(256), 0, stream, pix, uv, intr, extr, out);
}